// Round 4
// baseline (466.371 us; speedup 1.0000x reference)
//
#include <hip/hip_runtime.h>
#include <hip/hip_bf16.h>

typedef __attribute__((ext_vector_type(8))) __bf16 bf16x8;
typedef __attribute__((ext_vector_type(4))) float floatx4;
typedef __attribute__((ext_vector_type(8))) unsigned short ushort8;

namespace {
constexpr int kC  = 256;
constexpr int kNV = 1024 * 12;        // 12288
constexpr int kP  = 8 * kNV;          // 98304 positions
constexpr float kEps = 1e-5f;

// ws layout in float units
constexpr size_t OFF_PARAMS = 0;                         // 4 stages x [a(256)|b(256)]
constexpr size_t OFF_PART   = 2048;                      // 4 stages x 8 buckets x 512
constexpr size_t OFF_WB     = 2048 + 16384;              // 163840 ushort = 81920 floats (packed)
constexpr size_t OFF_XT     = OFF_WB + 81920;            // x transposed [P][256] bf16; stage4 overwrites in-place with x1
constexpr size_t OFF_Y1     = OFF_XT + (size_t)kP * 256 / 2;
constexpr size_t OFF_Y2     = OFF_Y1 + (size_t)kP * 64 / 2;   // [P][256] bf16 (also y4)
constexpr size_t OFF_Y3     = OFF_Y2 + (size_t)kP * 256 / 2;
} // namespace

__device__ __forceinline__ unsigned short f2bf(float f) {
    unsigned int u = __builtin_bit_cast(unsigned int, f);
    u += 0x7FFFu + ((u >> 16) & 1u);
    return (unsigned short)(u >> 16);
}
__device__ __forceinline__ float bf2f(unsigned short h) {
    unsigned int u = ((unsigned int)h) << 16;
    return __builtin_bit_cast(float, u);
}

// Pack the 4 weight matrices to bf16 in MFMA-fragment order:
// dst[base + (k/32)*(M*32) + m*32 + (k%32)]  (k-tile-major, then m, then k-within-tile)
__global__ void convw_kernel(const float* __restrict__ We, const float* __restrict__ Wa,
                             const float* __restrict__ Wo, const float* __restrict__ Wf,
                             unsigned short* __restrict__ dst)
{
    const int f = (blockIdx.x * 256 + threadIdx.x) * 4;
    const float* src; int off, M, K, base;
    if (f < 16384)      { src = We;            off = f;         M = 64;  K = 256; base = 0; }
    else if (f < 32768) { src = Wa + 512 * 64; off = f - 16384; M = 256; K = 64;  base = 16384; }
    else if (f < 98304) { src = Wo;            off = f - 32768; M = 256; K = 256; base = 32768; }
    else                { src = Wf;            off = f - 98304; M = 256; K = 256; base = 98304; }
    const int m = off / K, k = off - m * K;
    const float4 v = *(const float4*)&src[off];
    ushort4 o; o.x = f2bf(v.x); o.y = f2bf(v.y); o.z = f2bf(v.z); o.w = f2bf(v.w);
    *(ushort4*)&dst[base + (k >> 5) * (M * 32) + m * 32 + (k & 31)] = o;
}

// x [B,256,NV] fp32 channel-major -> xT [P][256] bf16 position-major
__global__ __launch_bounds__(256) void transpose_kernel(
    const float* __restrict__ x, unsigned short* __restrict__ xT)
{
    __shared__ float T[64][65];
    const int p0 = blockIdx.x * 64;      // never crosses b (kNV % 64 == 0)
    const int c0 = blockIdx.y * 64;
    const int b  = p0 / kNV;
    const int q0 = p0 - b * kNV;
    const int t  = threadIdx.x;

    const int cl = t >> 2;
    const int pq = (t & 3) * 16;
    const float* src = &x[(size_t)(b * kC + c0 + cl) * kNV + q0 + pq];
    #pragma unroll
    for (int i = 0; i < 4; ++i) {
        const float4 v = *(const float4*)&src[i * 4];
        T[cl][pq + i * 4 + 0] = v.x;
        T[cl][pq + i * 4 + 1] = v.y;
        T[cl][pq + i * 4 + 2] = v.z;
        T[cl][pq + i * 4 + 3] = v.w;
    }
    __syncthreads();
    const int pr = t >> 2;
    const int cb = (t & 3) * 16;
    #pragma unroll
    for (int i = 0; i < 2; ++i) {
        ushort8 o;
        #pragma unroll
        for (int j = 0; j < 8; ++j) o[j] = f2bf(T[cb + i * 8 + j][pr]);
        *(ushort8*)&xT[(size_t)(p0 + pr) * 256 + c0 + cb + i * 8] = o;
    }
}

template<int MODE>
__device__ __forceinline__ ushort8 xform(ushort8 y8, ushort8 x8, float mp,
                                         const float* __restrict__ actA,
                                         const float* __restrict__ actB, int kk)
{
    if constexpr (MODE == 0) {
        return y8;
    } else {
        const float4 a0 = *(const float4*)&actA[kk];
        const float4 a1 = *(const float4*)&actA[kk + 4];
        const float4 b0 = *(const float4*)&actB[kk];
        const float4 b1 = *(const float4*)&actB[kk + 4];
        const float aa[8] = {a0.x, a0.y, a0.z, a0.w, a1.x, a1.y, a1.z, a1.w};
        const float bb[8] = {b0.x, b0.y, b0.z, b0.w, b1.x, b1.y, b1.z, b1.w};
        ushort8 o;
        #pragma unroll
        for (int j = 0; j < 8; ++j) {
            float v = bf2f(y8[j]);
            v = mp * fmaxf(fmaf(aa[j], v, bb[j]), 0.f);
            if constexpr (MODE == 2) v += bf2f(x8[j]);
            o[j] = f2bf(v);
        }
        return o;
    }
}

// GEMM: Yout[p][m] = mask[p]*(sum_k W[m][k]*in[p][k] + bias[m]) over an exclusive
// 64-position slab per block (B read once from HBM by construction).
// A (weights) pre-packed in fragment order, loaded direct from global (L2-hot).
// B staged via double-buffered LDS, one barrier per 32-k iteration.
// MODE 0: in = raw bf16 [P][K].  MODE 1: in = mask*relu(a*y+b).
// MODE 2: MODE1 + xT residual; also writes x1 = result in-place into XT.
template<int BM, int K, int MODE>
__global__ __launch_bounds__(256, 2) void gemm_kernel(
    const unsigned short* __restrict__ Apk, const float* __restrict__ bias,
    const unsigned short* __restrict__ Yprev,
    unsigned short* __restrict__ XT,
    const float* __restrict__ mask,
    const float* __restrict__ actA, const float* __restrict__ actB,
    unsigned short* __restrict__ Yout, float* __restrict__ partial)
{
    constexpr int LD = 40;
    constexpr int FM = 4;
    constexpr int FP = (BM == 256) ? 4 : 1;
    constexpr int NT = K / 32;
    __shared__ unsigned short Bs[2][64 * LD];

    const int tid  = threadIdx.x;
    const int lane = tid & 63, w = tid >> 6, quad = lane >> 4, lt = lane & 15;
    const int mBase = (BM == 256) ? w * 64 : 0;
    const int pW    = (BM == 256) ? 0 : w * 16;
    const int pBase = blockIdx.x * 64;

    const int sp  = tid >> 2;          // 0..63 row of B slab
    const int skq = (tid & 3) * 8;     // 0,8,16,24
    const float mp = (MODE == 0) ? 0.f : mask[pBase + sp];

    floatx4 acc[FM][FP];
    #pragma unroll
    for (int fm = 0; fm < FM; ++fm)
        #pragma unroll
        for (int fp = 0; fp < FP; ++fp) acc[fm][fp] = (floatx4)0.f;

    // prologue: tile 0
    ushort8 by = *(const ushort8*)&Yprev[(size_t)(pBase + sp) * K + skq];
    ushort8 bx;
    if constexpr (MODE == 2) bx = *(const ushort8*)&XT[(size_t)(pBase + sp) * K + skq];
    ushort8 av[FM];
    #pragma unroll
    for (int fm = 0; fm < FM; ++fm)
        av[fm] = *(const ushort8*)&Apk[(size_t)(mBase + fm * 16 + lt) * 32 + quad * 8];
    {
        const ushort8 b0t = xform<MODE>(by, bx, mp, actA, actB, skq);
        if constexpr (MODE == 2)
            *(ushort8*)&XT[(size_t)(pBase + sp) * K + skq] = b0t;
        *(ushort8*)&Bs[0][sp * LD + skq] = b0t;
    }
    __syncthreads();

    for (int t = 0; t < NT; ++t) {
        ushort8 nby, nbx, nav[FM];
        if (t + 1 < NT) {
            const int kn = (t + 1) * 32;
            nby = *(const ushort8*)&Yprev[(size_t)(pBase + sp) * K + kn + skq];
            if constexpr (MODE == 2)
                nbx = *(const ushort8*)&XT[(size_t)(pBase + sp) * K + kn + skq];
            #pragma unroll
            for (int fm = 0; fm < FM; ++fm)
                nav[fm] = *(const ushort8*)&Apk[(size_t)((t + 1) * BM + mBase + fm * 16 + lt) * 32 + quad * 8];
        }
        bf16x8 bF[FP];
        #pragma unroll
        for (int fp = 0; fp < FP; ++fp)
            bF[fp] = *(const bf16x8*)&Bs[t & 1][(pW + fp * 16 + lt) * LD + quad * 8];
        #pragma unroll
        for (int fm = 0; fm < FM; ++fm) {
            const bf16x8 aF = __builtin_bit_cast(bf16x8, av[fm]);
            #pragma unroll
            for (int fp = 0; fp < FP; ++fp)
                acc[fm][fp] = __builtin_amdgcn_mfma_f32_16x16x32_bf16(aF, bF[fp], acc[fm][fp], 0, 0, 0);
        }
        if (t + 1 < NT) {
            const int kn = (t + 1) * 32;
            const ushort8 nb = xform<MODE>(nby, nbx, mp, actA, actB, kn + skq);
            if constexpr (MODE == 2)
                *(ushort8*)&XT[(size_t)(pBase + sp) * K + kn + skq] = nb;
            *(ushort8*)&Bs[(t + 1) & 1][sp * LD + skq] = nb;
            #pragma unroll
            for (int fm = 0; fm < FM; ++fm) av[fm] = nav[fm];
        }
        __syncthreads();
    }

    // epilogue: bias + mask, store bf16, fused BN stats
    float mpv[FP];
    #pragma unroll
    for (int fp = 0; fp < FP; ++fp) mpv[fp] = mask[pBase + pW + fp * 16 + lt];
    float sumv[FM][4], sqv[FM][4];
    #pragma unroll
    for (int fm = 0; fm < FM; ++fm)
        #pragma unroll
        for (int i = 0; i < 4; ++i) { sumv[fm][i] = 0.f; sqv[fm][i] = 0.f; }

    #pragma unroll
    for (int fm = 0; fm < FM; ++fm) {
        float bia[4];
        #pragma unroll
        for (int i = 0; i < 4; ++i) bia[i] = bias[mBase + fm * 16 + quad * 4 + i];
        #pragma unroll
        for (int fp = 0; fp < FP; ++fp) {
            const int pG = pBase + pW + fp * 16 + lt;
            float vv[4];
            #pragma unroll
            for (int i = 0; i < 4; ++i) {
                const float v = (acc[fm][fp][i] + bia[i]) * mpv[fp];
                vv[i] = v; sumv[fm][i] += v; sqv[fm][i] += v * v;
            }
            ushort4 o; o.x = f2bf(vv[0]); o.y = f2bf(vv[1]); o.z = f2bf(vv[2]); o.w = f2bf(vv[3]);
            *(ushort4*)&Yout[(size_t)pG * BM + mBase + fm * 16 + quad * 4] = o;
        }
    }
    #pragma unroll
    for (int fm = 0; fm < FM; ++fm)
        #pragma unroll
        for (int i = 0; i < 4; ++i) {
            #pragma unroll
            for (int off = 1; off < 16; off <<= 1) {
                sumv[fm][i] += __shfl_xor(sumv[fm][i], off);
                sqv[fm][i]  += __shfl_xor(sqv[fm][i], off);
            }
        }
    if (lt == 0) {
        float* part = partial + (size_t)(blockIdx.x & 7) * 512;
        #pragma unroll
        for (int fm = 0; fm < FM; ++fm)
            #pragma unroll
            for (int i = 0; i < 4; ++i) {
                const int cG = mBase + fm * 16 + quad * 4 + i;
                atomicAdd(&part[cG], sumv[fm][i]);
                atomicAdd(&part[256 + cG], sqv[fm][i]);
            }
    }
}

// fold BN into per-channel affine
__global__ void finalize_kernel(const float* __restrict__ part,
                                const float* __restrict__ g, const float* __restrict__ bt,
                                float* __restrict__ ab, int M)
{
    const int m = blockIdx.x * 64 + threadIdx.x;
    if (m >= M) return;
    float s = 0.f, s2 = 0.f;
    #pragma unroll
    for (int k = 0; k < 8; ++k) { s += part[k * 512 + m]; s2 += part[k * 512 + 256 + m]; }
    const float mu  = s * (1.f / kP);
    const float var = s2 * (1.f / kP) - mu * mu;
    const float A = rsqrtf(var + kEps) * g[m];
    ab[m] = A;
    ab[256 + m] = fmaf(-mu, A, bt[m]);
}

// out[c][q] = x1 + act4(y4); x1,y4 are [P][256] bf16 -> transpose via LDS
__global__ __launch_bounds__(256) void final_kernel(
    const unsigned short* __restrict__ x1, const unsigned short* __restrict__ y4,
    const float* __restrict__ p4, const float* __restrict__ mask, float* __restrict__ out)
{
    constexpr int TL = 264;
    __shared__ unsigned short TX[32 * TL];
    __shared__ unsigned short T4[32 * TL];
    const int p0 = blockIdx.x * 32;
    const int b  = p0 / kNV;
    const int q0 = p0 - b * kNV;

    #pragma unroll
    for (int i = 0; i < 4; ++i) {
        const int idx = threadIdx.x + i * 256;
        const int p = idx >> 5, c0 = (idx & 31) * 8;
        *(ushort8*)&TX[p * TL + c0] = *(const ushort8*)&x1[(size_t)(p0 + p) * 256 + c0];
        *(ushort8*)&T4[p * TL + c0] = *(const ushort8*)&y4[(size_t)(p0 + p) * 256 + c0];
    }
    __syncthreads();

    const int qv = (threadIdx.x & 15) * 2;
    const int cb = threadIdx.x >> 4;
    const float m0v = mask[p0 + qv], m1v = mask[p0 + qv + 1];
    #pragma unroll
    for (int j = 0; j < 16; ++j) {
        const int c = cb + j * 16;
        const float a4 = p4[c], b4 = p4[256 + c];
        const size_t ro = (size_t)(b * kC + c) * kNV + q0 + qv;
        float2 o;
        o.x = bf2f(TX[qv * TL + c])       + m0v * fmaxf(fmaf(a4, bf2f(T4[qv * TL + c]), b4), 0.f);
        o.y = bf2f(TX[(qv + 1) * TL + c]) + m1v * fmaxf(fmaf(a4, bf2f(T4[(qv + 1) * TL + c]), b4), 0.f);
        *(float2*)&out[ro] = o;
    }
}

extern "C" void kernel_launch(void* const* d_in, const int* in_sizes, int n_in,
                              void* d_out, int out_size, void* d_ws, size_t ws_size,
                              hipStream_t stream)
{
    const float* x    = (const float*)d_in[0];
    const float* mask = (const float*)d_in[1];
    const float* We   = (const float*)d_in[2];
    const float* be   = (const float*)d_in[3];
    const float* ge   = (const float*)d_in[4];
    const float* bne  = (const float*)d_in[5];
    const float* Wa   = (const float*)d_in[6];
    const float* ba   = (const float*)d_in[7];
    const float* ga   = (const float*)d_in[8];
    const float* bna  = (const float*)d_in[9];
    const float* Wo   = (const float*)d_in[10];
    const float* bo   = (const float*)d_in[11];
    const float* go   = (const float*)d_in[12];
    const float* bno  = (const float*)d_in[13];
    const float* Wf   = (const float*)d_in[14];
    const float* bf   = (const float*)d_in[15];
    const float* gf   = (const float*)d_in[16];
    const float* bnf  = (const float*)d_in[17];
    float* out = (float*)d_out;
    float* ws  = (float*)d_ws;

    float* params = ws + OFF_PARAMS;
    float* part   = ws + OFF_PART;
    unsigned short* Wb = (unsigned short*)(ws + OFF_WB);
    unsigned short* xT = (unsigned short*)(ws + OFF_XT);   // becomes x1 after stage 4
    unsigned short* y1 = (unsigned short*)(ws + OFF_Y1);
    unsigned short* y2 = (unsigned short*)(ws + OFF_Y2);   // later reused as y4
    unsigned short* y3 = (unsigned short*)(ws + OFF_Y3);

    hipMemsetAsync(part, 0, 16384 * sizeof(float), stream);
    convw_kernel<<<160, 256, 0, stream>>>(We, Wa, Wo, Wf, Wb);
    transpose_kernel<<<dim3(kP / 64, 4), 256, 0, stream>>>(x, xT);

    const dim3 blk(256);
    const dim3 grid(kP / 64);   // 1536 blocks, exclusive 64-position slab each

    // stage 1: y1 = mask*(We @ x + be)  [P][64]
    gemm_kernel<64, 256, 0><<<grid, blk, 0, stream>>>(
        Wb, be, xT, nullptr, mask, nullptr, nullptr, y1, part);
    finalize_kernel<<<1, 64, 0, stream>>>(part, ge, bne, params, 64);

    // stage 2: y2 = mask*(Wa_v @ act1(y1) + ba_v)  [P][256]
    gemm_kernel<256, 64, 1><<<grid, blk, 0, stream>>>(
        Wb + 16384, ba + 512, y1, nullptr, mask, params, params + 256, y2, part + 4096);
    finalize_kernel<<<4, 64, 0, stream>>>(part + 4096, ga + 512, bna + 512, params + 512, 256);

    // stage 3: y3 = mask*(Wo @ act2(y2) + bo)
    gemm_kernel<256, 256, 1><<<grid, blk, 0, stream>>>(
        Wb + 32768, bo, y2, nullptr, mask, params + 512, params + 768, y3, part + 8192);
    finalize_kernel<<<4, 64, 0, stream>>>(part + 8192, go, bno, params + 1024, 256);

    // stage 4: y4 = mask*(Wf @ x1 + bf), x1 = x + act3(y3) written in-place into xT
    gemm_kernel<256, 256, 2><<<grid, blk, 0, stream>>>(
        Wb + 98304, bf, y3, xT, mask, params + 1024, params + 1280, y2, part + 12288);
    finalize_kernel<<<4, 64, 0, stream>>>(part + 12288, gf, bnf, params + 1536, 256);

    // final: out = x1 + act4(y4)
    final_kernel<<<kP / 32, blk, 0, stream>>>(
        xT, y2, params + 1536, mask, out);
}

// Round 5
// 403.064 us; speedup vs baseline: 1.1571x; 1.1571x over previous
//
#include <hip/hip_runtime.h>
#include <hip/hip_bf16.h>

typedef __attribute__((ext_vector_type(8))) __bf16 bf16x8;
typedef __attribute__((ext_vector_type(4))) float floatx4;
typedef __attribute__((ext_vector_type(8))) unsigned short ushort8;

namespace {
constexpr int kC  = 256;
constexpr int kNV = 1024 * 12;        // 12288
constexpr int kP  = 8 * kNV;          // 98304 positions
constexpr float kEps = 1e-5f;

// ws layout in float units
constexpr size_t OFF_PARAMS = 0;                         // 4 stages x [a(256)|b(256)]
constexpr size_t OFF_PART   = 2048;                      // 4 stages x 8 buckets x 512
constexpr size_t OFF_WB     = 2048 + 16384;              // 163840 ushort = 81920 floats (packed)
constexpr size_t OFF_XT     = OFF_WB + 81920;            // x transposed [P][256] bf16; stage4 overwrites in-place with x1
constexpr size_t OFF_Y1     = OFF_XT + (size_t)kP * 256 / 2;
constexpr size_t OFF_Y2     = OFF_Y1 + (size_t)kP * 64 / 2;   // [P][256] bf16 (also y4)
constexpr size_t OFF_Y3     = OFF_Y2 + (size_t)kP * 256 / 2;
} // namespace

__device__ __forceinline__ unsigned short f2bf(float f) {
    unsigned int u = __builtin_bit_cast(unsigned int, f);
    u += 0x7FFFu + ((u >> 16) & 1u);
    return (unsigned short)(u >> 16);
}
__device__ __forceinline__ float bf2f(unsigned short h) {
    unsigned int u = ((unsigned int)h) << 16;
    return __builtin_bit_cast(float, u);
}

// Pack the 4 weight matrices to bf16 in MFMA-fragment order:
// dst[base + (k/32)*(M*32) + m*32 + (k%32)]
__global__ void convw_kernel(const float* __restrict__ We, const float* __restrict__ Wa,
                             const float* __restrict__ Wo, const float* __restrict__ Wf,
                             unsigned short* __restrict__ dst)
{
    const int f = (blockIdx.x * 256 + threadIdx.x) * 4;
    const float* src; int off, M, K, base;
    if (f < 16384)      { src = We;            off = f;         M = 64;  K = 256; base = 0; }
    else if (f < 32768) { src = Wa + 512 * 64; off = f - 16384; M = 256; K = 64;  base = 16384; }
    else if (f < 98304) { src = Wo;            off = f - 32768; M = 256; K = 256; base = 32768; }
    else                { src = Wf;            off = f - 98304; M = 256; K = 256; base = 98304; }
    const int m = off / K, k = off - m * K;
    const float4 v = *(const float4*)&src[off];
    ushort4 o; o.x = f2bf(v.x); o.y = f2bf(v.y); o.z = f2bf(v.z); o.w = f2bf(v.w);
    *(ushort4*)&dst[base + (k >> 5) * (M * 32) + m * 32 + (k & 31)] = o;
}

// x [B,256,NV] fp32 channel-major -> xT [P][256] bf16 position-major
__global__ __launch_bounds__(256) void transpose_kernel(
    const float* __restrict__ x, unsigned short* __restrict__ xT)
{
    __shared__ float T[64][65];
    const int p0 = blockIdx.x * 64;
    const int c0 = blockIdx.y * 64;
    const int b  = p0 / kNV;
    const int q0 = p0 - b * kNV;
    const int t  = threadIdx.x;

    const int cl = t >> 2;
    const int pq = (t & 3) * 16;
    const float* src = &x[(size_t)(b * kC + c0 + cl) * kNV + q0 + pq];
    #pragma unroll
    for (int i = 0; i < 4; ++i) {
        const float4 v = *(const float4*)&src[i * 4];
        T[cl][pq + i * 4 + 0] = v.x;
        T[cl][pq + i * 4 + 1] = v.y;
        T[cl][pq + i * 4 + 2] = v.z;
        T[cl][pq + i * 4 + 3] = v.w;
    }
    __syncthreads();
    const int pr = t >> 2;
    const int cb = (t & 3) * 16;
    #pragma unroll
    for (int i = 0; i < 2; ++i) {
        ushort8 o;
        #pragma unroll
        for (int j = 0; j < 8; ++j) o[j] = f2bf(T[cb + i * 8 + j][pr]);
        *(ushort8*)&xT[(size_t)(p0 + pr) * 256 + c0 + cb + i * 8] = o;
    }
}

template<int MODE>
__device__ __forceinline__ ushort8 xform(ushort8 y8, ushort8 x8, float mp,
                                         const float* __restrict__ actA,
                                         const float* __restrict__ actB, int kk)
{
    if constexpr (MODE == 0) {
        return y8;
    } else {
        const float4 a0 = *(const float4*)&actA[kk];
        const float4 a1 = *(const float4*)&actA[kk + 4];
        const float4 b0 = *(const float4*)&actB[kk];
        const float4 b1 = *(const float4*)&actB[kk + 4];
        const float aa[8] = {a0.x, a0.y, a0.z, a0.w, a1.x, a1.y, a1.z, a1.w};
        const float bb[8] = {b0.x, b0.y, b0.z, b0.w, b1.x, b1.y, b1.z, b1.w};
        ushort8 o;
        #pragma unroll
        for (int j = 0; j < 8; ++j) {
            float v = bf2f(y8[j]);
            v = mp * fmaxf(fmaf(aa[j], v, bb[j]), 0.f);
            if constexpr (MODE == 2) v += bf2f(x8[j]);
            o[j] = f2bf(v);
        }
        return o;
    }
}

// A-stationary GEMM. Block = 4 waves; wave owns BM/4 output channels with its FULL-K
// A fragments in registers (loaded once). B streams as 32-position slabs through a
// double-buffered LDS tile; ONE barrier per slab, 64 MFMAs/wave per slab (BM=256).
// Persistent block processes slabsPerBlock consecutive slabs.
// MODE 0: in raw bf16 [P][K]. MODE 1: in = mask*relu(a*y+b). MODE 2: MODE1 + XT
// residual, transformed value written back in-place to XT (becomes x1).
template<int BM, int K, int MODE>
__global__ __launch_bounds__(256, 2) void gemm_kernel(
    const unsigned short* __restrict__ Apk, const float* __restrict__ bias,
    const unsigned short* __restrict__ Yprev, unsigned short* __restrict__ XT,
    const float* __restrict__ mask,
    const float* __restrict__ actA, const float* __restrict__ actB,
    unsigned short* __restrict__ Yout, float* __restrict__ partial, int slabsPerBlock)
{
    constexpr int LD = 264;              // padded row stride (shorts): 2-way banks max
    constexpr int NT = K / 32;
    constexpr int FM = BM / 64;          // 4 (BM=256) or 1 (BM=64)
    constexpr int FP = 2;                // 32 positions per slab
    constexpr int CH = K / 64;           // ushort8 chunks per thread per stream
    __shared__ unsigned short Bs[2][32 * LD];
    __shared__ float Sst[2][256];

    const int tid  = threadIdx.x;
    const int w    = tid >> 6, lane = tid & 63, quad = lane >> 4, lt = lane & 15;
    const int mBase = w * 16 * FM;

    Sst[0][tid] = 0.f; Sst[1][tid] = 0.f;

    // ---- A fragments: full K, once per block (L2-hot) ----
    ushort8 Areg[NT][FM];
    #pragma unroll
    for (int t = 0; t < NT; ++t)
        #pragma unroll
        for (int fm = 0; fm < FM; ++fm)
            Areg[t][fm] = *(const ushort8*)&Apk[(size_t)(t * BM + mBase + fm * 16 + lt) * 32 + quad * 8];

    const int spb   = slabsPerBlock;
    const int slab0 = blockIdx.x * spb;

    // ---- prologue: stage slab 0 into Bs[0] ----
    {
        const int pBase = slab0 * 32;
        #pragma unroll
        for (int i = 0; i < CH; ++i) {
            const int c = tid + i * 256;
            const int p = c / (K / 8);
            const int kq = (c % (K / 8)) * 8;
            const ushort8 y8 = *(const ushort8*)&Yprev[(size_t)(pBase + p) * K + kq];
            ushort8 o;
            if constexpr (MODE == 0) o = y8;
            else {
                ushort8 x8{};
                if constexpr (MODE == 2) x8 = *(const ushort8*)&XT[(size_t)(pBase + p) * K + kq];
                o = xform<MODE>(y8, x8, mask[pBase + p], actA, actB, kq);
                if constexpr (MODE == 2) *(ushort8*)&XT[(size_t)(pBase + p) * K + kq] = o;
            }
            *(ushort8*)&Bs[0][p * LD + kq] = o;
        }
    }
    __syncthreads();

    for (int s = 0; s < spb; ++s) {
        const int pBase = (slab0 + s) * 32;
        const bool hasNext = (s + 1 < spb);

        // ---- prefetch next slab's streams into registers (latency covered by MFMAs) ----
        ushort8 py[CH];
        ushort8 px[(MODE == 2) ? CH : 1];
        if (hasNext) {
            const int pN = (slab0 + s + 1) * 32;
            #pragma unroll
            for (int i = 0; i < CH; ++i) {
                const int c = tid + i * 256;
                const int p = c / (K / 8);
                const int kq = (c % (K / 8)) * 8;
                py[i] = *(const ushort8*)&Yprev[(size_t)(pN + p) * K + kq];
                if constexpr (MODE == 2)
                    px[i] = *(const ushort8*)&XT[(size_t)(pN + p) * K + kq];
            }
        }

        // ---- MFMA over current slab: LDS-only inner loop ----
        floatx4 acc[FM][FP];
        #pragma unroll
        for (int fm = 0; fm < FM; ++fm)
            #pragma unroll
            for (int fp = 0; fp < FP; ++fp) acc[fm][fp] = (floatx4)0.f;

        const unsigned short* bs = &Bs[s & 1][0];
        #pragma unroll
        for (int t = 0; t < NT; ++t) {
            bf16x8 bF[FP];
            #pragma unroll
            for (int fp = 0; fp < FP; ++fp)
                bF[fp] = *(const bf16x8*)&bs[(fp * 16 + lt) * LD + t * 32 + quad * 8];
            #pragma unroll
            for (int fm = 0; fm < FM; ++fm) {
                const bf16x8 aF = __builtin_bit_cast(bf16x8, Areg[t][fm]);
                #pragma unroll
                for (int fp = 0; fp < FP; ++fp)
                    acc[fm][fp] = __builtin_amdgcn_mfma_f32_16x16x32_bf16(aF, bF[fp], acc[fm][fp], 0, 0, 0);
            }
        }

        // ---- epilogue: bias + mask, bf16 store, stats into LDS (owner lanes) ----
        float mpv[FP];
        #pragma unroll
        for (int fp = 0; fp < FP; ++fp) mpv[fp] = mask[pBase + fp * 16 + lt];

        float sS[FM][4], sQ[FM][4];
        #pragma unroll
        for (int fm = 0; fm < FM; ++fm)
            #pragma unroll
            for (int i = 0; i < 4; ++i) { sS[fm][i] = 0.f; sQ[fm][i] = 0.f; }

        #pragma unroll
        for (int fm = 0; fm < FM; ++fm) {
            const float4 bia = *(const float4*)&bias[mBase + fm * 16 + quad * 4];
            const float bi[4] = {bia.x, bia.y, bia.z, bia.w};
            #pragma unroll
            for (int fp = 0; fp < FP; ++fp) {
                const int pG = pBase + fp * 16 + lt;
                float vv[4];
                #pragma unroll
                for (int i = 0; i < 4; ++i) {
                    const float v = (acc[fm][fp][i] + bi[i]) * mpv[fp];
                    vv[i] = v; sS[fm][i] += v; sQ[fm][i] += v * v;
                }
                ushort4 o; o.x = f2bf(vv[0]); o.y = f2bf(vv[1]); o.z = f2bf(vv[2]); o.w = f2bf(vv[3]);
                *(ushort4*)&Yout[(size_t)pG * BM + mBase + fm * 16 + quad * 4] = o;
            }
        }
        #pragma unroll
        for (int fm = 0; fm < FM; ++fm)
            #pragma unroll
            for (int i = 0; i < 4; ++i) {
                #pragma unroll
                for (int off = 1; off < 16; off <<= 1) {
                    sS[fm][i] += __shfl_xor(sS[fm][i], off);
                    sQ[fm][i] += __shfl_xor(sQ[fm][i], off);
                }
            }
        if (lt == 0) {
            #pragma unroll
            for (int fm = 0; fm < FM; ++fm)
                #pragma unroll
                for (int i = 0; i < 4; ++i) {
                    const int ch = mBase + fm * 16 + quad * 4 + i;   // unique owner per ch
                    Sst[0][ch] += sS[fm][i];
                    Sst[1][ch] += sQ[fm][i];
                }
        }

        // ---- xform prefetched data, write other LDS buffer ----
        if (hasNext) {
            const int pN = (slab0 + s + 1) * 32;
            unsigned short* bn = &Bs[(s + 1) & 1][0];
            #pragma unroll
            for (int i = 0; i < CH; ++i) {
                const int c = tid + i * 256;
                const int p = c / (K / 8);
                const int kq = (c % (K / 8)) * 8;
                ushort8 o;
                if constexpr (MODE == 0) o = py[i];
                else {
                    ushort8 x8{};
                    if constexpr (MODE == 2) x8 = px[i];
                    o = xform<MODE>(py[i], x8, mask[pN + p], actA, actB, kq);
                    if constexpr (MODE == 2) *(ushort8*)&XT[(size_t)(pN + p) * K + kq] = o;
                }
                *(ushort8*)&bn[p * LD + kq] = o;
            }
        }
        __syncthreads();
    }

    // ---- flush block stats (one bucketed atomic pass) ----
    if (tid < BM) {
        float* pb = partial + (size_t)(blockIdx.x & 7) * 512;
        atomicAdd(&pb[tid], Sst[0][tid]);
        atomicAdd(&pb[256 + tid], Sst[1][tid]);
    }
}

// fold BN into per-channel affine
__global__ void finalize_kernel(const float* __restrict__ part,
                                const float* __restrict__ g, const float* __restrict__ bt,
                                float* __restrict__ ab, int M)
{
    const int m = blockIdx.x * 64 + threadIdx.x;
    if (m >= M) return;
    float s = 0.f, s2 = 0.f;
    #pragma unroll
    for (int k = 0; k < 8; ++k) { s += part[k * 512 + m]; s2 += part[k * 512 + 256 + m]; }
    const float mu  = s * (1.f / kP);
    const float var = s2 * (1.f / kP) - mu * mu;
    const float A = rsqrtf(var + kEps) * g[m];
    ab[m] = A;
    ab[256 + m] = fmaf(-mu, A, bt[m]);
}

// out[c][q] = x1 + act4(y4); x1,y4 are [P][256] bf16 -> transpose via LDS
__global__ __launch_bounds__(256) void final_kernel(
    const unsigned short* __restrict__ x1, const unsigned short* __restrict__ y4,
    const float* __restrict__ p4, const float* __restrict__ mask, float* __restrict__ out)
{
    constexpr int TL = 264;
    __shared__ unsigned short TX[32 * TL];
    __shared__ unsigned short T4[32 * TL];
    const int p0 = blockIdx.x * 32;
    const int b  = p0 / kNV;
    const int q0 = p0 - b * kNV;

    #pragma unroll
    for (int i = 0; i < 4; ++i) {
        const int idx = threadIdx.x + i * 256;
        const int p = idx >> 5, c0 = (idx & 31) * 8;
        *(ushort8*)&TX[p * TL + c0] = *(const ushort8*)&x1[(size_t)(p0 + p) * 256 + c0];
        *(ushort8*)&T4[p * TL + c0] = *(const ushort8*)&y4[(size_t)(p0 + p) * 256 + c0];
    }
    __syncthreads();

    const int qv = (threadIdx.x & 15) * 2;
    const int cb = threadIdx.x >> 4;
    const float m0v = mask[p0 + qv], m1v = mask[p0 + qv + 1];
    #pragma unroll
    for (int j = 0; j < 16; ++j) {
        const int c = cb + j * 16;
        const float a4 = p4[c], b4 = p4[256 + c];
        const size_t ro = (size_t)(b * kC + c) * kNV + q0 + qv;
        float2 o;
        o.x = bf2f(TX[qv * TL + c])       + m0v * fmaxf(fmaf(a4, bf2f(T4[qv * TL + c]), b4), 0.f);
        o.y = bf2f(TX[(qv + 1) * TL + c]) + m1v * fmaxf(fmaf(a4, bf2f(T4[(qv + 1) * TL + c]), b4), 0.f);
        *(float2*)&out[ro] = o;
    }
}

extern "C" void kernel_launch(void* const* d_in, const int* in_sizes, int n_in,
                              void* d_out, int out_size, void* d_ws, size_t ws_size,
                              hipStream_t stream)
{
    const float* x    = (const float*)d_in[0];
    const float* mask = (const float*)d_in[1];
    const float* We   = (const float*)d_in[2];
    const float* be   = (const float*)d_in[3];
    const float* ge   = (const float*)d_in[4];
    const float* bne  = (const float*)d_in[5];
    const float* Wa   = (const float*)d_in[6];
    const float* ba   = (const float*)d_in[7];
    const float* ga   = (const float*)d_in[8];
    const float* bna  = (const float*)d_in[9];
    const float* Wo   = (const float*)d_in[10];
    const float* bo   = (const float*)d_in[11];
    const float* go   = (const float*)d_in[12];
    const float* bno  = (const float*)d_in[13];
    const float* Wf   = (const float*)d_in[14];
    const float* bf   = (const float*)d_in[15];
    const float* gf   = (const float*)d_in[16];
    const float* bnf  = (const float*)d_in[17];
    float* out = (float*)d_out;
    float* ws  = (float*)d_ws;

    float* params = ws + OFF_PARAMS;
    float* part   = ws + OFF_PART;
    unsigned short* Wb = (unsigned short*)(ws + OFF_WB);
    unsigned short* xT = (unsigned short*)(ws + OFF_XT);   // becomes x1 after stage 4
    unsigned short* y1 = (unsigned short*)(ws + OFF_Y1);
    unsigned short* y2 = (unsigned short*)(ws + OFF_Y2);   // later reused as y4
    unsigned short* y3 = (unsigned short*)(ws + OFF_Y3);

    hipMemsetAsync(part, 0, 16384 * sizeof(float), stream);
    convw_kernel<<<160, 256, 0, stream>>>(We, Wa, Wo, Wf, Wb);
    transpose_kernel<<<dim3(kP / 64, 4), 256, 0, stream>>>(x, xT);

    const dim3 blk(256);
    const dim3 grid(512);             // 2 blocks/CU, fully resident
    const int SPB = kP / 32 / 512;    // 6 slabs of 32 positions per block

    // stage 1: y1 = mask*(We @ x + be)  [P][64]
    gemm_kernel<64, 256, 0><<<grid, blk, 0, stream>>>(
        Wb, be, xT, nullptr, mask, nullptr, nullptr, y1, part, SPB);
    finalize_kernel<<<1, 64, 0, stream>>>(part, ge, bne, params, 64);

    // stage 2: y2 = mask*(Wa_v @ act1(y1) + ba_v)  [P][256]
    gemm_kernel<256, 64, 1><<<grid, blk, 0, stream>>>(
        Wb + 16384, ba + 512, y1, nullptr, mask, params, params + 256, y2, part + 4096, SPB);
    finalize_kernel<<<4, 64, 0, stream>>>(part + 4096, ga + 512, bna + 512, params + 512, 256);

    // stage 3: y3 = mask*(Wo @ act2(y2) + bo)
    gemm_kernel<256, 256, 1><<<grid, blk, 0, stream>>>(
        Wb + 32768, bo, y2, nullptr, mask, params + 512, params + 768, y3, part + 8192, SPB);
    finalize_kernel<<<4, 64, 0, stream>>>(part + 8192, go, bno, params + 1024, 256);

    // stage 4: y4 = mask*(Wf @ x1 + bf), x1 = x + act3(y3) written in-place into xT
    gemm_kernel<256, 256, 2><<<grid, blk, 0, stream>>>(
        Wb + 98304, bf, y3, xT, mask, params + 1024, params + 1280, y2, part + 12288, SPB);
    finalize_kernel<<<4, 64, 0, stream>>>(part + 12288, gf, bnf, params + 1536, 256);

    // final: out = x1 + act4(y4)
    final_kernel<<<kP / 32, blk, 0, stream>>>(
        xT, y2, params + 1536, mask, out);
}